// Round 11
// baseline (345.305 us; speedup 1.0000x reference)
//
#include <hip/hip_runtime.h>
#include <stdint.h>

#define BATCH 32
#define SEQ   1024
#define DIM   64
#define NKT   (SEQ / 64)

typedef uint8_t  u8;
typedef uint16_t u16;
typedef uint32_t u32;
typedef unsigned long long u64;
typedef __attribute__((ext_vector_type(8))) __bf16 bf16x8;
typedef __attribute__((ext_vector_type(4))) float  f32x4;
typedef __attribute__((ext_vector_type(4))) u32    u32x4;

__device__ __forceinline__ float fexp2(float x) {
#if __has_builtin(__builtin_amdgcn_exp2f)
    return __builtin_amdgcn_exp2f(x);
#else
    return exp2f(x);
#endif
}

__device__ __forceinline__ u16 f2bf(float f) {
    u32 x = __builtin_bit_cast(u32, f);
    x += 0x7FFFu + ((x >> 16) & 1u);   // round-to-nearest-even
    return (u16)(x >> 16);
}

__device__ __forceinline__ bf16x8 cvt8(const float* __restrict__ p) {
    f32x4 a = *reinterpret_cast<const f32x4*>(p);
    f32x4 b = *reinterpret_cast<const f32x4*>(p + 4);
    u16 t[8];
    t[0] = f2bf(a[0]); t[1] = f2bf(a[1]); t[2] = f2bf(a[2]); t[3] = f2bf(a[3]);
    t[4] = f2bf(b[0]); t[5] = f2bf(b[1]); t[6] = f2bf(b[2]); t[7] = f2bf(b[3]);
    return __builtin_bit_cast(bf16x8, *reinterpret_cast<u32x4*>(t));
}

__device__ __forceinline__ bf16x8 cvt8s(const float* __restrict__ p, float s) {
    f32x4 a = *reinterpret_cast<const f32x4*>(p);
    f32x4 b = *reinterpret_cast<const f32x4*>(p + 4);
    u16 t[8];
    t[0] = f2bf(a[0] * s); t[1] = f2bf(a[1] * s); t[2] = f2bf(a[2] * s); t[3] = f2bf(a[3] * s);
    t[4] = f2bf(b[0] * s); t[5] = f2bf(b[1] * s); t[6] = f2bf(b[2] * s); t[7] = f2bf(b[3] * s);
    return __builtin_bit_cast(bf16x8, *reinterpret_cast<u32x4*>(t));
}

__device__ __forceinline__ bf16x8 ldg8(const u16* p) {
    u32x4 u = *reinterpret_cast<const u32x4*>(p);
    return __builtin_bit_cast(bf16x8, u);
}

// pack 4 ints' nonzero-ness into 4 bytes of a u32
__device__ __forceinline__ u32 pack4(u32x4 a) {
    return (u32)(a[0] != 0) | ((u32)(a[1] != 0) << 8) |
           ((u32)(a[2] != 0) << 16) | ((u32)(a[3] != 0) << 24);
}

// ---------------------------------------------------------------------------
// prep_kv (512 blocks): K f32 -> bf16 row-major; V f32 -> Vt bf16 [B][D][S].
// ---------------------------------------------------------------------------
__global__ __launch_bounds__(256) void prep_kv(
    const float* __restrict__ kg, const float* __restrict__ vg,
    u16* __restrict__ kb, u16* __restrict__ vtb_) {
    __shared__ u16 tile[64][72];
    const int t  = threadIdx.x;
    const int b  = blockIdx.x >> 4;
    const int k0 = (blockIdx.x & 15) * 64;

    {   // K f32 -> bf16 row-major (64x64 tile)
        int kk = t >> 2;
        int d0 = (t & 3) * 16;
        const float* src = kg + ((size_t)b * SEQ + k0 + kk) * DIM + d0;
        u16 tmp[16];
#pragma unroll
        for (int i = 0; i < 4; ++i) {
            f32x4 a = *reinterpret_cast<const f32x4*>(src + i * 4);
            tmp[i * 4 + 0] = f2bf(a[0]); tmp[i * 4 + 1] = f2bf(a[1]);
            tmp[i * 4 + 2] = f2bf(a[2]); tmp[i * 4 + 3] = f2bf(a[3]);
        }
        u16* dst = kb + ((size_t)b * SEQ + k0 + kk) * DIM + d0;
        *reinterpret_cast<u32x4*>(dst)     = *reinterpret_cast<u32x4*>(tmp);
        *reinterpret_cast<u32x4*>(dst + 8) = *reinterpret_cast<u32x4*>(tmp + 8);
    }
    {   // V tile -> LDS bf16 -> transposed store
        const float* vb = vg + (size_t)b * SEQ * DIM;
        int kk = t >> 2;
        int d0 = (t & 3) * 16;
        const float* src = vb + (size_t)(k0 + kk) * DIM + d0;
        u16 tmp[16];
#pragma unroll
        for (int i = 0; i < 4; ++i) {
            f32x4 a = *reinterpret_cast<const f32x4*>(src + i * 4);
            tmp[i * 4 + 0] = f2bf(a[0]); tmp[i * 4 + 1] = f2bf(a[1]);
            tmp[i * 4 + 2] = f2bf(a[2]); tmp[i * 4 + 3] = f2bf(a[3]);
        }
        *reinterpret_cast<u32x4*>(&tile[kk][d0])     = *reinterpret_cast<u32x4*>(tmp);
        *reinterpret_cast<u32x4*>(&tile[kk][d0 + 8]) = *reinterpret_cast<u32x4*>(tmp + 8);
    }
    __syncthreads();
    u16* vtb = vtb_ + (size_t)b * DIM * SEQ;
#pragma unroll
    for (int i = 0; i < 2; ++i) {
        int d  = t / 8 + i * 32;
        int ks = (t % 8) * 8;
        u16 tmp[8];
#pragma unroll
        for (int j = 0; j < 8; ++j) tmp[j] = tile[ks + j][d];
        *reinterpret_cast<u32x4*>(vtb + (size_t)d * SEQ + k0 + ks) =
            *reinterpret_cast<u32x4*>(tmp);
    }
}

// ---------------------------------------------------------------------------
// attn_fast11: r9 verbatim with ONE change: __launch_bounds__(512,4)
// (4 waves/EU -> 2 blocks/CU residency; VGPR cap 128, r9 used 96).
// Theory: the in-loop HBM mask stream is MLP-limited at 1 block/CU;
// doubling resident waves doubles outstanding requests.
// ---------------------------------------------------------------------------
__global__ __launch_bounds__(512, 4) void attn_fast11(
    const float* __restrict__ qg, const u16* __restrict__ kbf,
    const u16* __restrict__ vt, const int* __restrict__ maskg,
    const float* __restrict__ ptg, float* __restrict__ outg) {
    __shared__ float qp[64][132];        // 33792 B; reused as combine buffer
    __shared__ u16   plds[8][16][72];    // 18432 B, per-wave P tile
    __shared__ u8    mlds[8][16][64];    //  8192 B, per-wave mask byte tile

    const int b    = blockIdx.y;
    const int q0   = blockIdx.x * 64;
    const int tid  = threadIdx.x;
    const int wave = tid >> 6;
    const int lane = tid & 63;
    const int wq   = wave & 3;
    const int wk   = wave >> 2;
    const int quad = lane >> 4;
    const int c16  = lane & 15;

    const float SC = 0.125f * 1.44269504088896340736f;  // 1/8 * log2(e)

    const float* qb = qg + ((size_t)b * SEQ + q0) * DIM;

    // Q A-fragments, pre-scaled (exp2 space)
    const bf16x8 qA0 = cvt8s(qb + (size_t)(wq * 16 + c16) * DIM + quad * 8, SC);
    const bf16x8 qA1 = cvt8s(qb + (size_t)(wq * 16 + c16) * DIM + 32 + quad * 8, SC);

    // qp[64][129] = (SC*Q)(64x64) . pos_table^T ; jt tiles split across wk
    {
        const int jt0 = wk ? 5 : 0, jt1 = wk ? 9 : 5;
        for (int jt = jt0; jt < jt1; ++jt) {
            int j0 = jt * 16;
            int jr = min(j0 + c16, 128);
            bf16x8 b0 = cvt8(ptg + (size_t)jr * DIM + quad * 8);
            bf16x8 b1 = cvt8(ptg + (size_t)jr * DIM + 32 + quad * 8);
            f32x4 acc = {0.f, 0.f, 0.f, 0.f};
            acc = __builtin_amdgcn_mfma_f32_16x16x32_bf16(qA0, b0, acc, 0, 0, 0);
            acc = __builtin_amdgcn_mfma_f32_16x16x32_bf16(qA1, b1, acc, 0, 0, 0);
            int jcol = j0 + c16;
            if (jcol <= 128) {
#pragma unroll
                for (int r = 0; r < 4; ++r)
                    qp[wq * 16 + quad * 4 + r][jcol] = acc[r];
            }
        }
    }
    __syncthreads();   // qp complete (both halves)

    // per-row saturation constants (one broadcast LDS read each)
    float cL[4], cR[4];
#pragma unroll
    for (int r = 0; r < 4; ++r) {
        cL[r] = qp[wq * 16 + quad * 4 + r][0];
        cR[r] = qp[wq * 16 + quad * 4 + r][128];
    }

    const u16* kb_base  = kbf + (size_t)b * SEQ * DIM;
    const u16* vtb_base = vt  + (size_t)b * DIM * SEQ;
    const int  row_min  = q0 + wq * 16;
    const int  ktbase   = wk * 8;

    // int-mask source for this lane: row q0+wq*16+(lane>>2), 16-int chunk (lane&3)
    const int* mrow = maskg + ((size_t)b * SEQ + q0 + wq * 16 + (lane >> 2)) * SEQ +
                      (lane & 3) * 16;

    // 2-deep mask prefetch: mreg[0] = tile ktbase, mreg[1] = tile ktbase+1
    u32x4 mreg[2][4];
#pragma unroll
    for (int s = 0; s < 2; ++s) {
        const int* p = mrow + (size_t)(ktbase + s) * 64;
        mreg[s][0] = *reinterpret_cast<const u32x4*>(p);
        mreg[s][1] = *reinterpret_cast<const u32x4*>(p + 4);
        mreg[s][2] = *reinterpret_cast<const u32x4*>(p + 8);
        mreg[s][3] = *reinterpret_cast<const u32x4*>(p + 12);
    }

    // K fragments for first tile, prefetched into registers
    bf16x8 kc0[4], kc1[4];
#pragma unroll
    for (int sub = 0; sub < 4; ++sub) {
        const u16* kr = kb_base + (size_t)(ktbase * 64 + sub * 16 + c16) * DIM;
        kc0[sub] = ldg8(kr + quad * 8);
        kc1[sub] = ldg8(kr + 32 + quad * 8);
    }

    float l_part[4];
    f32x4 O[4];
#pragma unroll
    for (int r = 0; r < 4; ++r) l_part[r] = 0.f;
#pragma unroll
    for (int d = 0; d < 4; ++d) O[d] = f32x4{0.f, 0.f, 0.f, 0.f};

#pragma unroll
    for (int j = 0; j < 8; ++j) {
        const int kt = ktbase + j;
        const int k0 = kt * 64;
        const int ms = j & 1;          // static after full unroll

        // stage this tile's mask bytes (per-wave LDS, in-order, no barrier)
        {
            u32x4 pk;
            pk[0] = pack4(mreg[ms][0]); pk[1] = pack4(mreg[ms][1]);
            pk[2] = pack4(mreg[ms][2]); pk[3] = pack4(mreg[ms][3]);
            *reinterpret_cast<u32x4*>(&mlds[wave][lane >> 2][(lane & 3) * 16]) = pk;
        }
        // refill this set with tile kt+2 (wrapped in-bounds; tail values unused)
        {
            const int* p = mrow + (size_t)((kt + 2) & 15) * 64;
            mreg[ms][0] = *reinterpret_cast<const u32x4*>(p);
            mreg[ms][1] = *reinterpret_cast<const u32x4*>(p + 4);
            mreg[ms][2] = *reinterpret_cast<const u32x4*>(p + 8);
            mreg[ms][3] = *reinterpret_cast<const u32x4*>(p + 12);
        }

        // --- S = (SC*Q) . K^T from prefetched registers --------------------
        f32x4 S[4];
        __builtin_amdgcn_s_setprio(1);
#pragma unroll
        for (int sub = 0; sub < 4; ++sub) {
            f32x4 acc = {0.f, 0.f, 0.f, 0.f};
            acc = __builtin_amdgcn_mfma_f32_16x16x32_bf16(qA0, kc0[sub], acc, 0, 0, 0);
            acc = __builtin_amdgcn_mfma_f32_16x16x32_bf16(qA1, kc1[sub], acc, 0, 0, 0);
            S[sub] = acc;
        }
        __builtin_amdgcn_s_setprio(0);

        // --- refill K registers with next tile (wrapped; hidden under exp) -
        {
            const int kn = (ktbase + ((j + 1) & 7)) * 64;
#pragma unroll
            for (int sub = 0; sub < 4; ++sub) {
                const u16* kr = kb_base + (size_t)(kn + sub * 16 + c16) * DIM;
                kc0[sub] = ldg8(kr + quad * 8);
                kc1[sub] = ldg8(kr + 32 + quad * 8);
            }
        }

        // --- issue current V loads early (consumed after exp work) ---------
        bf16x8 vf0[4], vf1[4];
#pragma unroll
        for (int d = 0; d < 4; ++d) {
            const u16* vr = vtb_base + (size_t)(d * 16 + c16) * SEQ + k0;
            vf0[d] = ldg8(vr + quad * 8);
            vf1[d] = ldg8(vr + 32 + quad * 8);
        }

        // --- logits -> e = exp2(.) raw; lane-local l; P to LDS -------------
        const bool farL = (k0 + 127 <= row_min);
        const bool farR = (k0 >= row_min + 79);

        if (farL | farR) {
#pragma unroll
            for (int r = 0; r < 4; ++r) {
                const int row_l = quad * 4 + r;
                const float c = farL ? cL[r] : cR[r];
                float rs = 0.f;
#pragma unroll
                for (int sub = 0; sub < 4; ++sub) {
                    u8 mv = mlds[wave][row_l][sub * 16 + c16];
                    float e = mv ? 0.f : fexp2(S[sub][r] + c);
                    rs += e;
                    plds[wave][row_l][sub * 16 + c16] = f2bf(e);
                }
                l_part[r] += rs;
            }
        } else {
#pragma unroll
            for (int r = 0; r < 4; ++r) {
                const int row_l = quad * 4 + r;
                const int row_g = row_min + row_l;
                float rs = 0.f;
#pragma unroll
                for (int sub = 0; sub < 4; ++sub) {
                    int col_g = k0 + sub * 16 + c16;
                    int rel = col_g - row_g;
                    rel = rel < -64 ? -64 : (rel > 64 ? 64 : rel);
                    float x = S[sub][r] + qp[wq * 16 + row_l][rel + 64];
                    u8 mv = mlds[wave][row_l][sub * 16 + c16];
                    float e = mv ? 0.f : fexp2(x);
                    rs += e;
                    plds[wave][row_l][sub * 16 + c16] = f2bf(e);
                }
                l_part[r] += rs;
            }
        }

        // --- P (A-layout from per-wave LDS) and PV accumulate --------------
        bf16x8 pA0 = *reinterpret_cast<bf16x8*>(&plds[wave][c16][quad * 8]);
        bf16x8 pA1 = *reinterpret_cast<bf16x8*>(&plds[wave][c16][32 + quad * 8]);
        __builtin_amdgcn_s_setprio(1);
#pragma unroll
        for (int d = 0; d < 4; ++d) {
            O[d] = __builtin_amdgcn_mfma_f32_16x16x32_bf16(pA0, vf0[d], O[d], 0, 0, 0);
            O[d] = __builtin_amdgcn_mfma_f32_16x16x32_bf16(pA1, vf1[d], O[d], 0, 0, 0);
        }
        __builtin_amdgcn_s_setprio(0);
    }

    // --- one l reduce at the end -------------------------------------------
    float l_run[4];
#pragma unroll
    for (int r = 0; r < 4; ++r) {
        float rs = l_part[r];
        rs += __shfl_xor(rs, 1);
        rs += __shfl_xor(rs, 2);
        rs += __shfl_xor(rs, 4);
        rs += __shfl_xor(rs, 8);
        l_run[r] = rs;
    }

    // --- merge the two K-halves: plain adds (same zero shift both) ---------
    __syncthreads();   // everyone done reading qp
    float* cmb = &qp[0][0];
    const int cbase = (wq * 64 + lane) * 24;
    if (wk == 1) {
#pragma unroll
        for (int r = 0; r < 4; ++r) cmb[cbase + r] = l_run[r];
#pragma unroll
        for (int d = 0; d < 4; ++d)
#pragma unroll
            for (int r = 0; r < 4; ++r)
                cmb[cbase + 4 + d * 4 + r] = O[d][r];
    }
    __syncthreads();
    if (wk == 0) {
        float* ob = outg + ((size_t)b * SEQ + q0) * DIM;
#pragma unroll
        for (int r = 0; r < 4; ++r) {
            float inv = 1.f / (l_run[r] + cmb[cbase + r]);
            int row_l = wq * 16 + quad * 4 + r;
#pragma unroll
            for (int d = 0; d < 4; ++d) {
                float o = O[d][r] + cmb[cbase + 4 + d * 4 + r];
                ob[(size_t)row_l * DIM + d * 16 + c16] = o * inv;
            }
        }
    }
}

// ---------------------------------------------------------------------------
// Fallback kernels (workspace too small for fast path).
// ---------------------------------------------------------------------------
__global__ __launch_bounds__(256) void vt_kernel(const float* __restrict__ v,
                                                 u16* __restrict__ vt) {
    __shared__ u16 tile[64][72];
    const int b  = blockIdx.y;
    const int k0 = blockIdx.x * 64;
    const int t  = threadIdx.x;
    const float* vb  = v  + (size_t)b * SEQ * DIM;
    u16*         vtb = vt + (size_t)b * DIM * SEQ;

    {
        int kk = t >> 2;
        int d0 = (t & 3) * 16;
        const float* src = vb + (size_t)(k0 + kk) * DIM + d0;
        u16 tmp[16];
#pragma unroll
        for (int i = 0; i < 4; ++i) {
            f32x4 a = *reinterpret_cast<const f32x4*>(src + i * 4);
            tmp[i * 4 + 0] = f2bf(a[0]); tmp[i * 4 + 1] = f2bf(a[1]);
            tmp[i * 4 + 2] = f2bf(a[2]); tmp[i * 4 + 3] = f2bf(a[3]);
        }
        *reinterpret_cast<u32x4*>(&tile[kk][d0])     = *reinterpret_cast<u32x4*>(tmp);
        *reinterpret_cast<u32x4*>(&tile[kk][d0 + 8]) = *reinterpret_cast<u32x4*>(tmp + 8);
    }
    __syncthreads();
#pragma unroll
    for (int i = 0; i < 2; ++i) {
        int d  = t / 8 + i * 32;
        int ks = (t % 8) * 8;
        u16 tmp[8];
#pragma unroll
        for (int j = 0; j < 8; ++j) tmp[j] = tile[ks + j][d];
        *reinterpret_cast<u32x4*>(vtb + (size_t)d * SEQ + k0 + ks) =
            *reinterpret_cast<u32x4*>(tmp);
    }
}

template <bool USE_VT>
__global__ __launch_bounds__(256, 2) void attn_kernel(
    const float* __restrict__ qg, const float* __restrict__ kg,
    const void* __restrict__ vgv, const int* __restrict__ maskg,
    const float* __restrict__ ptg, float* __restrict__ outg) {
    __shared__ float qp[64][132];
    __shared__ int   mlds[4][16][68];
    __shared__ u16   plds[4][16][72];

    const int b    = blockIdx.y;
    const int q0   = blockIdx.x * 64;
    const int tid  = threadIdx.x;
    const int wave = tid >> 6;
    const int lane = tid & 63;
    const int quad = lane >> 4;
    const int c16  = lane & 15;

    const float* qb = qg + ((size_t)b * SEQ + q0) * DIM;
    const float* kb = kg + (size_t)b * SEQ * DIM;
    const int*   mb = maskg + ((size_t)b * SEQ + q0) * SEQ;

    const bf16x8 qA0 = cvt8(qb + (size_t)(wave * 16 + c16) * DIM + quad * 8);
    const bf16x8 qA1 = cvt8(qb + (size_t)(wave * 16 + c16) * DIM + 32 + quad * 8);

    for (int jt = 0; jt < 9; ++jt) {
        int j0 = jt * 16;
        int jr = min(j0 + c16, 128);
        bf16x8 b0 = cvt8(ptg + (size_t)jr * DIM + quad * 8);
        bf16x8 b1 = cvt8(ptg + (size_t)jr * DIM + 32 + quad * 8);
        f32x4 acc = {0.f, 0.f, 0.f, 0.f};
        acc = __builtin_amdgcn_mfma_f32_16x16x32_bf16(qA0, b0, acc, 0, 0, 0);
        acc = __builtin_amdgcn_mfma_f32_16x16x32_bf16(qA1, b1, acc, 0, 0, 0);
        int jcol = j0 + c16;
        if (jcol <= 128) {
#pragma unroll
            for (int r = 0; r < 4; ++r)
                qp[wave * 16 + quad * 4 + r][jcol] = acc[r];
        }
    }

    float m_run[4], l_run[4];
    f32x4 O[4];
#pragma unroll
    for (int r = 0; r < 4; ++r) { m_run[r] = -1e30f; l_run[r] = 0.f; }
#pragma unroll
    for (int d = 0; d < 4; ++d) O[d] = f32x4{0.f, 0.f, 0.f, 0.f};

#pragma unroll 1
    for (int kt = 0; kt < NKT; ++kt) {
        const int k0 = kt * 64;
        {
            int row_l = lane >> 2;
            const int* mrow = mb + (size_t)(wave * 16 + row_l) * SEQ + k0;
#pragma unroll
            for (int i = 0; i < 4; ++i) {
                int seg = (lane & 3) + i * 4;
                *reinterpret_cast<u32x4*>(&mlds[wave][row_l][seg * 4]) =
                    *reinterpret_cast<const u32x4*>(mrow + seg * 4);
            }
        }

        f32x4 S[4];
#pragma unroll
        for (int sub = 0; sub < 4; ++sub) {
            const float* kr = kb + (size_t)(k0 + sub * 16 + c16) * DIM;
            bf16x8 kb0 = cvt8(kr + quad * 8);
            bf16x8 kb1 = cvt8(kr + 32 + quad * 8);
            f32x4 acc = {0.f, 0.f, 0.f, 0.f};
            acc = __builtin_amdgcn_mfma_f32_16x16x32_bf16(qA0, kb0, acc, 0, 0, 0);
            acc = __builtin_amdgcn_mfma_f32_16x16x32_bf16(qA1, kb1, acc, 0, 0, 0);
            S[sub] = acc;
        }

        float sv[4][4];
#pragma unroll
        for (int sub = 0; sub < 4; ++sub) {
#pragma unroll
            for (int r = 0; r < 4; ++r) {
                int row_l = quad * 4 + r;
                int row_g = q0 + wave * 16 + row_l;
                int col_g = k0 + sub * 16 + c16;
                int rel = col_g - row_g;
                rel = rel < -64 ? -64 : (rel > 64 ? 64 : rel);
                float x = (S[sub][r] + qp[wave * 16 + row_l][rel + 64]) * 0.125f;
                int mv = mlds[wave][row_l][sub * 16 + c16];
                sv[sub][r] = mv ? -1e30f : x;
            }
        }

        float m_new[4], alpha[4];
#pragma unroll
        for (int r = 0; r < 4; ++r) {
            float rmax = fmaxf(fmaxf(sv[0][r], sv[1][r]), fmaxf(sv[2][r], sv[3][r]));
            rmax = fmaxf(rmax, __shfl_xor(rmax, 1));
            rmax = fmaxf(rmax, __shfl_xor(rmax, 2));
            rmax = fmaxf(rmax, __shfl_xor(rmax, 4));
            rmax = fmaxf(rmax, __shfl_xor(rmax, 8));
            m_new[r] = fmaxf(m_run[r], rmax);
            alpha[r] = __expf(m_run[r] - m_new[r]);
            m_run[r] = m_new[r];
        }
#pragma unroll
        for (int r = 0; r < 4; ++r) {
            float rs = 0.f;
#pragma unroll
            for (int sub = 0; sub < 4; ++sub) {
                float e = __expf(sv[sub][r] - m_new[r]);
                rs += e;
                plds[wave][quad * 4 + r][sub * 16 + c16] = f2bf(e);
            }
            rs += __shfl_xor(rs, 1);
            rs += __shfl_xor(rs, 2);
            rs += __shfl_xor(rs, 4);
            rs += __shfl_xor(rs, 8);
            l_run[r] = l_run[r] * alpha[r] + rs;
#pragma unroll
            for (int d = 0; d < 4; ++d) O[d][r] *= alpha[r];
        }

        bf16x8 pA0 = *reinterpret_cast<bf16x8*>(&plds[wave][c16][quad * 8]);
        bf16x8 pA1 = *reinterpret_cast<bf16x8*>(&plds[wave][c16][32 + quad * 8]);
#pragma unroll
        for (int d = 0; d < 4; ++d) {
            bf16x8 vb0, vb1;
            if (USE_VT) {
                const u16* vtb = (const u16*)vgv + (size_t)b * DIM * SEQ +
                                 (size_t)(d * 16 + c16) * SEQ + k0;
                vb0 = ldg8(vtb + quad * 8);
                vb1 = ldg8(vtb + 32 + quad * 8);
            } else {
                u16 t0[8], t1[8];
                const float* vbase = (const float*)vgv +
                                     ((size_t)b * SEQ + k0) * DIM + d * 16 + c16;
#pragma unroll
                for (int jj = 0; jj < 8; ++jj) {
                    t0[jj] = f2bf(vbase[(size_t)(quad * 8 + jj) * DIM]);
                    t1[jj] = f2bf(vbase[(size_t)(32 + quad * 8 + jj) * DIM]);
                }
                vb0 = __builtin_bit_cast(bf16x8, *reinterpret_cast<u32x4*>(t0));
                vb1 = __builtin_bit_cast(bf16x8, *reinterpret_cast<u32x4*>(t1));
            }
            O[d] = __builtin_amdgcn_mfma_f32_16x16x32_bf16(pA0, vb0, O[d], 0, 0, 0);
            O[d] = __builtin_amdgcn_mfma_f32_16x16x32_bf16(pA1, vb1, O[d], 0, 0, 0);
        }
    }

    float* ob = outg + ((size_t)b * SEQ + q0) * DIM;
#pragma unroll
    for (int r = 0; r < 4; ++r) {
        float inv = 1.f / l_run[r];
        int row_l = wave * 16 + quad * 4 + r;
#pragma unroll
        for (int d = 0; d < 4; ++d)
            ob[(size_t)row_l * DIM + d * 16 + c16] = O[d][r] * inv;
    }
}

// ---------------------------------------------------------------------------
extern "C" void kernel_launch(void* const* d_in, const int* in_sizes, int n_in,
                              void* d_out, int out_size, void* d_ws, size_t ws_size,
                              hipStream_t stream) {
    const float* q    = (const float*)d_in[0];
    const float* k    = (const float*)d_in[1];
    const float* v    = (const float*)d_in[2];
    const int*   mask = (const int*)d_in[3];
    const float* pt   = (const float*)d_in[4];
    float* out        = (float*)d_out;

    const size_t vt_bytes = (size_t)BATCH * SEQ * DIM * sizeof(u16);   // 4 MB
    const size_t kb_bytes = (size_t)BATCH * SEQ * DIM * sizeof(u16);   // 4 MB
    dim3 grid(SEQ / 64, BATCH);

    if (ws_size >= vt_bytes + kb_bytes) {
        u16* vt = (u16*)d_ws;
        u16* kb = (u16*)((char*)d_ws + vt_bytes);
        prep_kv<<<dim3(512), 256, 0, stream>>>(k, v, kb, vt);
        attn_fast11<<<grid, 512, 0, stream>>>(q, kb, vt, mask, pt, out);
    } else if (ws_size >= vt_bytes) {
        u16* vt = (u16*)d_ws;
        vt_kernel<<<grid, 256, 0, stream>>>(v, vt);
        attn_kernel<true><<<grid, 256, 0, stream>>>(q, k, (const void*)vt, mask, pt, out);
    } else {
        attn_kernel<false><<<grid, 256, 0, stream>>>(q, k, (const void*)v, mask, pt, out);
    }
}

// Round 12
// 265.516 us; speedup vs baseline: 1.3005x; 1.3005x over previous
//
#include <hip/hip_runtime.h>
#include <stdint.h>

#define BATCH 32
#define SEQ   1024
#define DIM   64
#define NKT   (SEQ / 64)

typedef uint8_t  u8;
typedef uint16_t u16;
typedef uint32_t u32;
typedef unsigned long long u64;
typedef __attribute__((ext_vector_type(8))) __bf16 bf16x8;
typedef __attribute__((ext_vector_type(4))) float  f32x4;
typedef __attribute__((ext_vector_type(4))) u32    u32x4;

__device__ __forceinline__ float fexp2(float x) {
#if __has_builtin(__builtin_amdgcn_exp2f)
    return __builtin_amdgcn_exp2f(x);
#else
    return exp2f(x);
#endif
}

__device__ __forceinline__ u16 f2bf(float f) {
    u32 x = __builtin_bit_cast(u32, f);
    x += 0x7FFFu + ((x >> 16) & 1u);   // round-to-nearest-even
    return (u16)(x >> 16);
}

__device__ __forceinline__ bf16x8 cvt8(const float* __restrict__ p) {
    f32x4 a = *reinterpret_cast<const f32x4*>(p);
    f32x4 b = *reinterpret_cast<const f32x4*>(p + 4);
    u16 t[8];
    t[0] = f2bf(a[0]); t[1] = f2bf(a[1]); t[2] = f2bf(a[2]); t[3] = f2bf(a[3]);
    t[4] = f2bf(b[0]); t[5] = f2bf(b[1]); t[6] = f2bf(b[2]); t[7] = f2bf(b[3]);
    return __builtin_bit_cast(bf16x8, *reinterpret_cast<u32x4*>(t));
}

__device__ __forceinline__ bf16x8 cvt8s(const float* __restrict__ p, float s) {
    f32x4 a = *reinterpret_cast<const f32x4*>(p);
    f32x4 b = *reinterpret_cast<const f32x4*>(p + 4);
    u16 t[8];
    t[0] = f2bf(a[0] * s); t[1] = f2bf(a[1] * s); t[2] = f2bf(a[2] * s); t[3] = f2bf(a[3] * s);
    t[4] = f2bf(b[0] * s); t[5] = f2bf(b[1] * s); t[6] = f2bf(b[2] * s); t[7] = f2bf(b[3] * s);
    return __builtin_bit_cast(bf16x8, *reinterpret_cast<u32x4*>(t));
}

__device__ __forceinline__ bf16x8 ldg8(const u16* p) {
    u32x4 u = *reinterpret_cast<const u32x4*>(p);
    return __builtin_bit_cast(bf16x8, u);
}

// pack 4 ints' nonzero-ness into 4 bytes of a u32
__device__ __forceinline__ u32 pack4(u32x4 a) {
    return (u32)(a[0] != 0) | ((u32)(a[1] != 0) << 8) |
           ((u32)(a[2] != 0) << 16) | ((u32)(a[3] != 0) << 24);
}

// ---------------------------------------------------------------------------
// prep_kv (512 blocks): K f32 -> bf16 row-major; V f32 -> Vt bf16 [B][D][S].
// ---------------------------------------------------------------------------
__global__ __launch_bounds__(256) void prep_kv(
    const float* __restrict__ kg, const float* __restrict__ vg,
    u16* __restrict__ kb, u16* __restrict__ vtb_) {
    __shared__ u16 tile[64][72];
    const int t  = threadIdx.x;
    const int b  = blockIdx.x >> 4;
    const int k0 = (blockIdx.x & 15) * 64;

    {   // K f32 -> bf16 row-major (64x64 tile)
        int kk = t >> 2;
        int d0 = (t & 3) * 16;
        const float* src = kg + ((size_t)b * SEQ + k0 + kk) * DIM + d0;
        u16 tmp[16];
#pragma unroll
        for (int i = 0; i < 4; ++i) {
            f32x4 a = *reinterpret_cast<const f32x4*>(src + i * 4);
            tmp[i * 4 + 0] = f2bf(a[0]); tmp[i * 4 + 1] = f2bf(a[1]);
            tmp[i * 4 + 2] = f2bf(a[2]); tmp[i * 4 + 3] = f2bf(a[3]);
        }
        u16* dst = kb + ((size_t)b * SEQ + k0 + kk) * DIM + d0;
        *reinterpret_cast<u32x4*>(dst)     = *reinterpret_cast<u32x4*>(tmp);
        *reinterpret_cast<u32x4*>(dst + 8) = *reinterpret_cast<u32x4*>(tmp + 8);
    }
    {   // V tile -> LDS bf16 -> transposed store
        const float* vb = vg + (size_t)b * SEQ * DIM;
        int kk = t >> 2;
        int d0 = (t & 3) * 16;
        const float* src = vb + (size_t)(k0 + kk) * DIM + d0;
        u16 tmp[16];
#pragma unroll
        for (int i = 0; i < 4; ++i) {
            f32x4 a = *reinterpret_cast<const f32x4*>(src + i * 4);
            tmp[i * 4 + 0] = f2bf(a[0]); tmp[i * 4 + 1] = f2bf(a[1]);
            tmp[i * 4 + 2] = f2bf(a[2]); tmp[i * 4 + 3] = f2bf(a[3]);
        }
        *reinterpret_cast<u32x4*>(&tile[kk][d0])     = *reinterpret_cast<u32x4*>(tmp);
        *reinterpret_cast<u32x4*>(&tile[kk][d0 + 8]) = *reinterpret_cast<u32x4*>(tmp + 8);
    }
    __syncthreads();
    u16* vtb = vtb_ + (size_t)b * DIM * SEQ;
#pragma unroll
    for (int i = 0; i < 2; ++i) {
        int d  = t / 8 + i * 32;
        int ks = (t % 8) * 8;
        u16 tmp[8];
#pragma unroll
        for (int j = 0; j < 8; ++j) tmp[j] = tile[ks + j][d];
        *reinterpret_cast<u32x4*>(vtb + (size_t)d * SEQ + k0 + ks) =
            *reinterpret_cast<u32x4*>(tmp);
    }
}

// ---------------------------------------------------------------------------
// attn_fast12: r9 with deeper static pipeline:
//  - __launch_bounds__(512) (no min-waves arg): VGPR cap lifted so the
//    compiler can hoist loads across the fully-unrolled 8-iter loop.
//    (Empirical: (512,2)->128 cap, (512,4)->64 cap+spill. No arg = free.)
//  - 4-deep mask prefetch mreg[4][4] (16x16B in flight/lane, static idx).
//  - mlds row stride 64 -> 80 B (4-way -> 2-way bank aliasing; 2-way free).
// Everything else identical to passing r9 (no-max softmax, K reg-prefetch,
// V early-issue, far-tile shortcut, plain-add merge).
// ---------------------------------------------------------------------------
__global__ __launch_bounds__(512) void attn_fast12(
    const float* __restrict__ qg, const u16* __restrict__ kbf,
    const u16* __restrict__ vt, const int* __restrict__ maskg,
    const float* __restrict__ ptg, float* __restrict__ outg) {
    __shared__ float qp[64][132];        // 33792 B; reused as combine buffer
    __shared__ u16   plds[8][16][72];    // 18432 B, per-wave P tile
    __shared__ u8    mlds[8][16][80];    // 10240 B, per-wave mask byte tile
    // total 62464 B (< 64 KB per-workgroup max)

    const int b    = blockIdx.y;
    const int q0   = blockIdx.x * 64;
    const int tid  = threadIdx.x;
    const int wave = tid >> 6;
    const int lane = tid & 63;
    const int wq   = wave & 3;
    const int wk   = wave >> 2;
    const int quad = lane >> 4;
    const int c16  = lane & 15;

    const float SC = 0.125f * 1.44269504088896340736f;  // 1/8 * log2(e)

    const float* qb = qg + ((size_t)b * SEQ + q0) * DIM;

    // Q A-fragments, pre-scaled (exp2 space)
    const bf16x8 qA0 = cvt8s(qb + (size_t)(wq * 16 + c16) * DIM + quad * 8, SC);
    const bf16x8 qA1 = cvt8s(qb + (size_t)(wq * 16 + c16) * DIM + 32 + quad * 8, SC);

    // qp[64][129] = (SC*Q)(64x64) . pos_table^T ; jt tiles split across wk
    {
        const int jt0 = wk ? 5 : 0, jt1 = wk ? 9 : 5;
        for (int jt = jt0; jt < jt1; ++jt) {
            int j0 = jt * 16;
            int jr = min(j0 + c16, 128);
            bf16x8 b0 = cvt8(ptg + (size_t)jr * DIM + quad * 8);
            bf16x8 b1 = cvt8(ptg + (size_t)jr * DIM + 32 + quad * 8);
            f32x4 acc = {0.f, 0.f, 0.f, 0.f};
            acc = __builtin_amdgcn_mfma_f32_16x16x32_bf16(qA0, b0, acc, 0, 0, 0);
            acc = __builtin_amdgcn_mfma_f32_16x16x32_bf16(qA1, b1, acc, 0, 0, 0);
            int jcol = j0 + c16;
            if (jcol <= 128) {
#pragma unroll
                for (int r = 0; r < 4; ++r)
                    qp[wq * 16 + quad * 4 + r][jcol] = acc[r];
            }
        }
    }
    __syncthreads();   // qp complete (both halves)

    // per-row saturation constants (one broadcast LDS read each)
    float cL[4], cR[4];
#pragma unroll
    for (int r = 0; r < 4; ++r) {
        cL[r] = qp[wq * 16 + quad * 4 + r][0];
        cR[r] = qp[wq * 16 + quad * 4 + r][128];
    }

    const u16* kb_base  = kbf + (size_t)b * SEQ * DIM;
    const u16* vtb_base = vt  + (size_t)b * DIM * SEQ;
    const int  row_min  = q0 + wq * 16;
    const int  ktbase   = wk * 8;

    // int-mask source for this lane: row q0+wq*16+(lane>>2), 16-int chunk (lane&3)
    const int* mrow = maskg + ((size_t)b * SEQ + q0 + wq * 16 + (lane >> 2)) * SEQ +
                      (lane & 3) * 16;

    // 4-deep mask prefetch: mreg[s] = tile ktbase+s
    u32x4 mreg[4][4];
#pragma unroll
    for (int s = 0; s < 4; ++s) {
        const int* p = mrow + (size_t)(ktbase + s) * 64;
        mreg[s][0] = *reinterpret_cast<const u32x4*>(p);
        mreg[s][1] = *reinterpret_cast<const u32x4*>(p + 4);
        mreg[s][2] = *reinterpret_cast<const u32x4*>(p + 8);
        mreg[s][3] = *reinterpret_cast<const u32x4*>(p + 12);
    }

    // K fragments for first tile, prefetched into registers
    bf16x8 kc0[4], kc1[4];
#pragma unroll
    for (int sub = 0; sub < 4; ++sub) {
        const u16* kr = kb_base + (size_t)(ktbase * 64 + sub * 16 + c16) * DIM;
        kc0[sub] = ldg8(kr + quad * 8);
        kc1[sub] = ldg8(kr + 32 + quad * 8);
    }

    float l_part[4];
    f32x4 O[4];
#pragma unroll
    for (int r = 0; r < 4; ++r) l_part[r] = 0.f;
#pragma unroll
    for (int d = 0; d < 4; ++d) O[d] = f32x4{0.f, 0.f, 0.f, 0.f};

#pragma unroll
    for (int j = 0; j < 8; ++j) {
        const int kt = ktbase + j;
        const int k0 = kt * 64;
        const int ms = j & 3;          // static after full unroll

        // stage this tile's mask bytes (per-wave LDS, in-order, no barrier)
        {
            u32x4 pk;
            pk[0] = pack4(mreg[ms][0]); pk[1] = pack4(mreg[ms][1]);
            pk[2] = pack4(mreg[ms][2]); pk[3] = pack4(mreg[ms][3]);
            *reinterpret_cast<u32x4*>(&mlds[wave][lane >> 2][(lane & 3) * 16]) = pk;
        }
        // refill this slot with tile kt+4 (wrapped in-bounds; tail unused)
        {
            const int* p = mrow + (size_t)((kt + 4) & 15) * 64;
            mreg[ms][0] = *reinterpret_cast<const u32x4*>(p);
            mreg[ms][1] = *reinterpret_cast<const u32x4*>(p + 4);
            mreg[ms][2] = *reinterpret_cast<const u32x4*>(p + 8);
            mreg[ms][3] = *reinterpret_cast<const u32x4*>(p + 12);
        }

        // --- S = (SC*Q) . K^T from prefetched registers --------------------
        f32x4 S[4];
        __builtin_amdgcn_s_setprio(1);
#pragma unroll
        for (int sub = 0; sub < 4; ++sub) {
            f32x4 acc = {0.f, 0.f, 0.f, 0.f};
            acc = __builtin_amdgcn_mfma_f32_16x16x32_bf16(qA0, kc0[sub], acc, 0, 0, 0);
            acc = __builtin_amdgcn_mfma_f32_16x16x32_bf16(qA1, kc1[sub], acc, 0, 0, 0);
            S[sub] = acc;
        }
        __builtin_amdgcn_s_setprio(0);

        // --- refill K registers with next tile (wrapped; hidden under exp) -
        {
            const int kn = (ktbase + ((j + 1) & 7)) * 64;
#pragma unroll
            for (int sub = 0; sub < 4; ++sub) {
                const u16* kr = kb_base + (size_t)(kn + sub * 16 + c16) * DIM;
                kc0[sub] = ldg8(kr + quad * 8);
                kc1[sub] = ldg8(kr + 32 + quad * 8);
            }
        }

        // --- issue current V loads early (consumed after exp work) ---------
        bf16x8 vf0[4], vf1[4];
#pragma unroll
        for (int d = 0; d < 4; ++d) {
            const u16* vr = vtb_base + (size_t)(d * 16 + c16) * SEQ + k0;
            vf0[d] = ldg8(vr + quad * 8);
            vf1[d] = ldg8(vr + 32 + quad * 8);
        }

        // --- logits -> e = exp2(.) raw; lane-local l; P to LDS -------------
        const bool farL = (k0 + 127 <= row_min);
        const bool farR = (k0 >= row_min + 79);

        if (farL | farR) {
#pragma unroll
            for (int r = 0; r < 4; ++r) {
                const int row_l = quad * 4 + r;
                const float c = farL ? cL[r] : cR[r];
                float rs = 0.f;
#pragma unroll
                for (int sub = 0; sub < 4; ++sub) {
                    u8 mv = mlds[wave][row_l][sub * 16 + c16];
                    float e = mv ? 0.f : fexp2(S[sub][r] + c);
                    rs += e;
                    plds[wave][row_l][sub * 16 + c16] = f2bf(e);
                }
                l_part[r] += rs;
            }
        } else {
#pragma unroll
            for (int r = 0; r < 4; ++r) {
                const int row_l = quad * 4 + r;
                const int row_g = row_min + row_l;
                float rs = 0.f;
#pragma unroll
                for (int sub = 0; sub < 4; ++sub) {
                    int col_g = k0 + sub * 16 + c16;
                    int rel = col_g - row_g;
                    rel = rel < -64 ? -64 : (rel > 64 ? 64 : rel);
                    float x = S[sub][r] + qp[wq * 16 + row_l][rel + 64];
                    u8 mv = mlds[wave][row_l][sub * 16 + c16];
                    float e = mv ? 0.f : fexp2(x);
                    rs += e;
                    plds[wave][row_l][sub * 16 + c16] = f2bf(e);
                }
                l_part[r] += rs;
            }
        }

        // --- P (A-layout from per-wave LDS) and PV accumulate --------------
        bf16x8 pA0 = *reinterpret_cast<bf16x8*>(&plds[wave][c16][quad * 8]);
        bf16x8 pA1 = *reinterpret_cast<bf16x8*>(&plds[wave][c16][32 + quad * 8]);
        __builtin_amdgcn_s_setprio(1);
#pragma unroll
        for (int d = 0; d < 4; ++d) {
            O[d] = __builtin_amdgcn_mfma_f32_16x16x32_bf16(pA0, vf0[d], O[d], 0, 0, 0);
            O[d] = __builtin_amdgcn_mfma_f32_16x16x32_bf16(pA1, vf1[d], O[d], 0, 0, 0);
        }
        __builtin_amdgcn_s_setprio(0);
    }

    // --- one l reduce at the end -------------------------------------------
    float l_run[4];
#pragma unroll
    for (int r = 0; r < 4; ++r) {
        float rs = l_part[r];
        rs += __shfl_xor(rs, 1);
        rs += __shfl_xor(rs, 2);
        rs += __shfl_xor(rs, 4);
        rs += __shfl_xor(rs, 8);
        l_run[r] = rs;
    }

    // --- merge the two K-halves: plain adds (same zero shift both) ---------
    __syncthreads();   // everyone done reading qp
    float* cmb = &qp[0][0];
    const int cbase = (wq * 64 + lane) * 24;
    if (wk == 1) {
#pragma unroll
        for (int r = 0; r < 4; ++r) cmb[cbase + r] = l_run[r];
#pragma unroll
        for (int d = 0; d < 4; ++d)
#pragma unroll
            for (int r = 0; r < 4; ++r)
                cmb[cbase + 4 + d * 4 + r] = O[d][r];
    }
    __syncthreads();
    if (wk == 0) {
        float* ob = outg + ((size_t)b * SEQ + q0) * DIM;
#pragma unroll
        for (int r = 0; r < 4; ++r) {
            float inv = 1.f / (l_run[r] + cmb[cbase + r]);
            int row_l = wq * 16 + quad * 4 + r;
#pragma unroll
            for (int d = 0; d < 4; ++d) {
                float o = O[d][r] + cmb[cbase + 4 + d * 4 + r];
                ob[(size_t)row_l * DIM + d * 16 + c16] = o * inv;
            }
        }
    }
}

// ---------------------------------------------------------------------------
// Fallback kernels (workspace too small for fast path).
// ---------------------------------------------------------------------------
__global__ __launch_bounds__(256) void vt_kernel(const float* __restrict__ v,
                                                 u16* __restrict__ vt) {
    __shared__ u16 tile[64][72];
    const int b  = blockIdx.y;
    const int k0 = blockIdx.x * 64;
    const int t  = threadIdx.x;
    const float* vb  = v  + (size_t)b * SEQ * DIM;
    u16*         vtb = vt + (size_t)b * DIM * SEQ;

    {
        int kk = t >> 2;
        int d0 = (t & 3) * 16;
        const float* src = vb + (size_t)(k0 + kk) * DIM + d0;
        u16 tmp[16];
#pragma unroll
        for (int i = 0; i < 4; ++i) {
            f32x4 a = *reinterpret_cast<const f32x4*>(src + i * 4);
            tmp[i * 4 + 0] = f2bf(a[0]); tmp[i * 4 + 1] = f2bf(a[1]);
            tmp[i * 4 + 2] = f2bf(a[2]); tmp[i * 4 + 3] = f2bf(a[3]);
        }
        *reinterpret_cast<u32x4*>(&tile[kk][d0])     = *reinterpret_cast<u32x4*>(tmp);
        *reinterpret_cast<u32x4*>(&tile[kk][d0 + 8]) = *reinterpret_cast<u32x4*>(tmp + 8);
    }
    __syncthreads();
#pragma unroll
    for (int i = 0; i < 2; ++i) {
        int d  = t / 8 + i * 32;
        int ks = (t % 8) * 8;
        u16 tmp[8];
#pragma unroll
        for (int j = 0; j < 8; ++j) tmp[j] = tile[ks + j][d];
        *reinterpret_cast<u32x4*>(vtb + (size_t)d * SEQ + k0 + ks) =
            *reinterpret_cast<u32x4*>(tmp);
    }
}

template <bool USE_VT>
__global__ __launch_bounds__(256, 2) void attn_kernel(
    const float* __restrict__ qg, const float* __restrict__ kg,
    const void* __restrict__ vgv, const int* __restrict__ maskg,
    const float* __restrict__ ptg, float* __restrict__ outg) {
    __shared__ float qp[64][132];
    __shared__ int   mlds[4][16][68];
    __shared__ u16   plds[4][16][72];

    const int b    = blockIdx.y;
    const int q0   = blockIdx.x * 64;
    const int tid  = threadIdx.x;
    const int wave = tid >> 6;
    const int lane = tid & 63;
    const int quad = lane >> 4;
    const int c16  = lane & 15;

    const float* qb = qg + ((size_t)b * SEQ + q0) * DIM;
    const float* kb = kg + (size_t)b * SEQ * DIM;
    const int*   mb = maskg + ((size_t)b * SEQ + q0) * SEQ;

    const bf16x8 qA0 = cvt8(qb + (size_t)(wave * 16 + c16) * DIM + quad * 8);
    const bf16x8 qA1 = cvt8(qb + (size_t)(wave * 16 + c16) * DIM + 32 + quad * 8);

    for (int jt = 0; jt < 9; ++jt) {
        int j0 = jt * 16;
        int jr = min(j0 + c16, 128);
        bf16x8 b0 = cvt8(ptg + (size_t)jr * DIM + quad * 8);
        bf16x8 b1 = cvt8(ptg + (size_t)jr * DIM + 32 + quad * 8);
        f32x4 acc = {0.f, 0.f, 0.f, 0.f};
        acc = __builtin_amdgcn_mfma_f32_16x16x32_bf16(qA0, b0, acc, 0, 0, 0);
        acc = __builtin_amdgcn_mfma_f32_16x16x32_bf16(qA1, b1, acc, 0, 0, 0);
        int jcol = j0 + c16;
        if (jcol <= 128) {
#pragma unroll
            for (int r = 0; r < 4; ++r)
                qp[wave * 16 + quad * 4 + r][jcol] = acc[r];
        }
    }

    float m_run[4], l_run[4];
    f32x4 O[4];
#pragma unroll
    for (int r = 0; r < 4; ++r) { m_run[r] = -1e30f; l_run[r] = 0.f; }
#pragma unroll
    for (int d = 0; d < 4; ++d) O[d] = f32x4{0.f, 0.f, 0.f, 0.f};

#pragma unroll 1
    for (int kt = 0; kt < NKT; ++kt) {
        const int k0 = kt * 64;
        {
            int row_l = lane >> 2;
            const int* mrow = mb + (size_t)(wave * 16 + row_l) * SEQ + k0;
#pragma unroll
            for (int i = 0; i < 4; ++i) {
                int seg = (lane & 3) + i * 4;
                *reinterpret_cast<u32x4*>(&mlds[wave][row_l][seg * 4]) =
                    *reinterpret_cast<const u32x4*>(mrow + seg * 4);
            }
        }

        f32x4 S[4];
#pragma unroll
        for (int sub = 0; sub < 4; ++sub) {
            const float* kr = kb + (size_t)(k0 + sub * 16 + c16) * DIM;
            bf16x8 kb0 = cvt8(kr + quad * 8);
            bf16x8 kb1 = cvt8(kr + 32 + quad * 8);
            f32x4 acc = {0.f, 0.f, 0.f, 0.f};
            acc = __builtin_amdgcn_mfma_f32_16x16x32_bf16(qA0, kb0, acc, 0, 0, 0);
            acc = __builtin_amdgcn_mfma_f32_16x16x32_bf16(qA1, kb1, acc, 0, 0, 0);
            S[sub] = acc;
        }

        float sv[4][4];
#pragma unroll
        for (int sub = 0; sub < 4; ++sub) {
#pragma unroll
            for (int r = 0; r < 4; ++r) {
                int row_l = quad * 4 + r;
                int row_g = q0 + wave * 16 + row_l;
                int col_g = k0 + sub * 16 + c16;
                int rel = col_g - row_g;
                rel = rel < -64 ? -64 : (rel > 64 ? 64 : rel);
                float x = (S[sub][r] + qp[wave * 16 + row_l][rel + 64]) * 0.125f;
                int mv = mlds[wave][row_l][sub * 16 + c16];
                sv[sub][r] = mv ? -1e30f : x;
            }
        }

        float m_new[4], alpha[4];
#pragma unroll
        for (int r = 0; r < 4; ++r) {
            float rmax = fmaxf(fmaxf(sv[0][r], sv[1][r]), fmaxf(sv[2][r], sv[3][r]));
            rmax = fmaxf(rmax, __shfl_xor(rmax, 1));
            rmax = fmaxf(rmax, __shfl_xor(rmax, 2));
            rmax = fmaxf(rmax, __shfl_xor(rmax, 4));
            rmax = fmaxf(rmax, __shfl_xor(rmax, 8));
            m_new[r] = fmaxf(m_run[r], rmax);
            alpha[r] = __expf(m_run[r] - m_new[r]);
            m_run[r] = m_new[r];
        }
#pragma unroll
        for (int r = 0; r < 4; ++r) {
            float rs = 0.f;
#pragma unroll
            for (int sub = 0; sub < 4; ++sub) {
                float e = __expf(sv[sub][r] - m_new[r]);
                rs += e;
                plds[wave][quad * 4 + r][sub * 16 + c16] = f2bf(e);
            }
            rs += __shfl_xor(rs, 1);
            rs += __shfl_xor(rs, 2);
            rs += __shfl_xor(rs, 4);
            rs += __shfl_xor(rs, 8);
            l_run[r] = l_run[r] * alpha[r] + rs;
#pragma unroll
            for (int d = 0; d < 4; ++d) O[d][r] *= alpha[r];
        }

        bf16x8 pA0 = *reinterpret_cast<bf16x8*>(&plds[wave][c16][quad * 8]);
        bf16x8 pA1 = *reinterpret_cast<bf16x8*>(&plds[wave][c16][32 + quad * 8]);
#pragma unroll
        for (int d = 0; d < 4; ++d) {
            bf16x8 vb0, vb1;
            if (USE_VT) {
                const u16* vtb = (const u16*)vgv + (size_t)b * DIM * SEQ +
                                 (size_t)(d * 16 + c16) * SEQ + k0;
                vb0 = ldg8(vtb + quad * 8);
                vb1 = ldg8(vtb + 32 + quad * 8);
            } else {
                u16 t0[8], t1[8];
                const float* vbase = (const float*)vgv +
                                     ((size_t)b * SEQ + k0) * DIM + d * 16 + c16;
#pragma unroll
                for (int jj = 0; jj < 8; ++jj) {
                    t0[jj] = f2bf(vbase[(size_t)(quad * 8 + jj) * DIM]);
                    t1[jj] = f2bf(vbase[(size_t)(32 + quad * 8 + jj) * DIM]);
                }
                vb0 = __builtin_bit_cast(bf16x8, *reinterpret_cast<u32x4*>(t0));
                vb1 = __builtin_bit_cast(bf16x8, *reinterpret_cast<u32x4*>(t1));
            }
            O[d] = __builtin_amdgcn_mfma_f32_16x16x32_bf16(pA0, vb0, O[d], 0, 0, 0);
            O[d] = __builtin_amdgcn_mfma_f32_16x16x32_bf16(pA1, vb1, O[d], 0, 0, 0);
        }
    }

    float* ob = outg + ((size_t)b * SEQ + q0) * DIM;
#pragma unroll
    for (int r = 0; r < 4; ++r) {
        float inv = 1.f / l_run[r];
        int row_l = wave * 16 + quad * 4 + r;
#pragma unroll
        for (int d = 0; d < 4; ++d)
            ob[(size_t)row_l * DIM + d * 16 + c16] = O[d][r] * inv;
    }
}

// ---------------------------------------------------------------------------
extern "C" void kernel_launch(void* const* d_in, const int* in_sizes, int n_in,
                              void* d_out, int out_size, void* d_ws, size_t ws_size,
                              hipStream_t stream) {
    const float* q    = (const float*)d_in[0];
    const float* k    = (const float*)d_in[1];
    const float* v    = (const float*)d_in[2];
    const int*   mask = (const int*)d_in[3];
    const float* pt   = (const float*)d_in[4];
    float* out        = (float*)d_out;

    const size_t vt_bytes = (size_t)BATCH * SEQ * DIM * sizeof(u16);   // 4 MB
    const size_t kb_bytes = (size_t)BATCH * SEQ * DIM * sizeof(u16);   // 4 MB
    dim3 grid(SEQ / 64, BATCH);

    if (ws_size >= vt_bytes + kb_bytes) {
        u16* vt = (u16*)d_ws;
        u16* kb = (u16*)((char*)d_ws + vt_bytes);
        prep_kv<<<dim3(512), 256, 0, stream>>>(k, v, kb, vt);
        attn_fast12<<<grid, 512, 0, stream>>>(q, kb, vt, mask, pt, out);
    } else if (ws_size >= vt_bytes) {
        u16* vt = (u16*)d_ws;
        vt_kernel<<<grid, 256, 0, stream>>>(v, vt);
        attn_kernel<true><<<grid, 256, 0, stream>>>(q, k, (const void*)vt, mask, pt, out);
    } else {
        attn_kernel<false><<<grid, 256, 0, stream>>>(q, k, (const void*)v, mask, pt, out);
    }
}

// Round 13
// 255.119 us; speedup vs baseline: 1.3535x; 1.0408x over previous
//
#include <hip/hip_runtime.h>
#include <stdint.h>

#define BATCH 32
#define SEQ   1024
#define DIM   64
#define NKT   (SEQ / 64)

typedef uint8_t  u8;
typedef uint16_t u16;
typedef uint32_t u32;
typedef unsigned long long u64;
typedef __attribute__((ext_vector_type(8))) __bf16 bf16x8;
typedef __attribute__((ext_vector_type(4))) float  f32x4;
typedef __attribute__((ext_vector_type(4))) u32    u32x4;

__device__ __forceinline__ float fexp2(float x) {
#if __has_builtin(__builtin_amdgcn_exp2f)
    return __builtin_amdgcn_exp2f(x);
#else
    return exp2f(x);
#endif
}

__device__ __forceinline__ u16 f2bf(float f) {
    u32 x = __builtin_bit_cast(u32, f);
    x += 0x7FFFu + ((x >> 16) & 1u);   // round-to-nearest-even
    return (u16)(x >> 16);
}

__device__ __forceinline__ bf16x8 cvt8(const float* __restrict__ p) {
    f32x4 a = *reinterpret_cast<const f32x4*>(p);
    f32x4 b = *reinterpret_cast<const f32x4*>(p + 4);
    u16 t[8];
    t[0] = f2bf(a[0]); t[1] = f2bf(a[1]); t[2] = f2bf(a[2]); t[3] = f2bf(a[3]);
    t[4] = f2bf(b[0]); t[5] = f2bf(b[1]); t[6] = f2bf(b[2]); t[7] = f2bf(b[3]);
    return __builtin_bit_cast(bf16x8, *reinterpret_cast<u32x4*>(t));
}

__device__ __forceinline__ bf16x8 cvt8s(const float* __restrict__ p, float s) {
    f32x4 a = *reinterpret_cast<const f32x4*>(p);
    f32x4 b = *reinterpret_cast<const f32x4*>(p + 4);
    u16 t[8];
    t[0] = f2bf(a[0] * s); t[1] = f2bf(a[1] * s); t[2] = f2bf(a[2] * s); t[3] = f2bf(a[3] * s);
    t[4] = f2bf(b[0] * s); t[5] = f2bf(b[1] * s); t[6] = f2bf(b[2] * s); t[7] = f2bf(b[3] * s);
    return __builtin_bit_cast(bf16x8, *reinterpret_cast<u32x4*>(t));
}

__device__ __forceinline__ bf16x8 ldg8(const u16* p) {
    u32x4 u = *reinterpret_cast<const u32x4*>(p);
    return __builtin_bit_cast(bf16x8, u);
}

// pack 4 ints' nonzero-ness into 4 bytes of a u32
__device__ __forceinline__ u32 pack4(u32x4 a) {
    return (u32)(a[0] != 0) | ((u32)(a[1] != 0) << 8) |
           ((u32)(a[2] != 0) << 16) | ((u32)(a[3] != 0) << 24);
}

// ---------------------------------------------------------------------------
// prep_kv (512 blocks): K f32 -> bf16 row-major; V f32 -> Vt bf16 [B][D][S].
// ---------------------------------------------------------------------------
__global__ __launch_bounds__(256) void prep_kv(
    const float* __restrict__ kg, const float* __restrict__ vg,
    u16* __restrict__ kb, u16* __restrict__ vtb_) {
    __shared__ u16 tile[64][72];
    const int t  = threadIdx.x;
    const int b  = blockIdx.x >> 4;
    const int k0 = (blockIdx.x & 15) * 64;

    {   // K f32 -> bf16 row-major (64x64 tile)
        int kk = t >> 2;
        int d0 = (t & 3) * 16;
        const float* src = kg + ((size_t)b * SEQ + k0 + kk) * DIM + d0;
        u16 tmp[16];
#pragma unroll
        for (int i = 0; i < 4; ++i) {
            f32x4 a = *reinterpret_cast<const f32x4*>(src + i * 4);
            tmp[i * 4 + 0] = f2bf(a[0]); tmp[i * 4 + 1] = f2bf(a[1]);
            tmp[i * 4 + 2] = f2bf(a[2]); tmp[i * 4 + 3] = f2bf(a[3]);
        }
        u16* dst = kb + ((size_t)b * SEQ + k0 + kk) * DIM + d0;
        *reinterpret_cast<u32x4*>(dst)     = *reinterpret_cast<u32x4*>(tmp);
        *reinterpret_cast<u32x4*>(dst + 8) = *reinterpret_cast<u32x4*>(tmp + 8);
    }
    {   // V tile -> LDS bf16 -> transposed store
        const float* vb = vg + (size_t)b * SEQ * DIM;
        int kk = t >> 2;
        int d0 = (t & 3) * 16;
        const float* src = vb + (size_t)(k0 + kk) * DIM + d0;
        u16 tmp[16];
#pragma unroll
        for (int i = 0; i < 4; ++i) {
            f32x4 a = *reinterpret_cast<const f32x4*>(src + i * 4);
            tmp[i * 4 + 0] = f2bf(a[0]); tmp[i * 4 + 1] = f2bf(a[1]);
            tmp[i * 4 + 2] = f2bf(a[2]); tmp[i * 4 + 3] = f2bf(a[3]);
        }
        *reinterpret_cast<u32x4*>(&tile[kk][d0])     = *reinterpret_cast<u32x4*>(tmp);
        *reinterpret_cast<u32x4*>(&tile[kk][d0 + 8]) = *reinterpret_cast<u32x4*>(tmp + 8);
    }
    __syncthreads();
    u16* vtb = vtb_ + (size_t)b * DIM * SEQ;
#pragma unroll
    for (int i = 0; i < 2; ++i) {
        int d  = t / 8 + i * 32;
        int ks = (t % 8) * 8;
        u16 tmp[8];
#pragma unroll
        for (int j = 0; j < 8; ++j) tmp[j] = tile[ks + j][d];
        *reinterpret_cast<u32x4*>(vtb + (size_t)d * SEQ + k0 + ks) =
            *reinterpret_cast<u32x4*>(tmp);
    }
}

// ---------------------------------------------------------------------------
// attn_fast13: r9 with the iteration MODULO-SCHEDULED (rotated one stage):
//   loop j: mask(j) -> exp(j) from CARRIED S_cur (no mem wait) ->
//           S(j+1) from K loaded last iter (also covers plds w->r gap) ->
//           PV(j) from V issued last iter -> issue V(j+1), K(j+2).
// Every global load has >= 1 full iteration of cover. Numerically identical
// to r9 (same ops, reordered). __launch_bounds__(512): cap lifted (r12).
// ---------------------------------------------------------------------------
__global__ __launch_bounds__(512) void attn_fast13(
    const float* __restrict__ qg, const u16* __restrict__ kbf,
    const u16* __restrict__ vt, const int* __restrict__ maskg,
    const float* __restrict__ ptg, float* __restrict__ outg) {
    __shared__ float qp[64][132];        // 33792 B; reused as combine buffer
    __shared__ u16   plds[8][16][72];    // 18432 B, per-wave P tile
    __shared__ u8    mlds[8][16][64];    //  8192 B, per-wave mask byte tile

    const int b    = blockIdx.y;
    const int q0   = blockIdx.x * 64;
    const int tid  = threadIdx.x;
    const int wave = tid >> 6;
    const int lane = tid & 63;
    const int wq   = wave & 3;
    const int wk   = wave >> 2;
    const int quad = lane >> 4;
    const int c16  = lane & 15;

    const float SC = 0.125f * 1.44269504088896340736f;  // 1/8 * log2(e)

    const float* qb = qg + ((size_t)b * SEQ + q0) * DIM;

    // Q A-fragments, pre-scaled (exp2 space)
    const bf16x8 qA0 = cvt8s(qb + (size_t)(wq * 16 + c16) * DIM + quad * 8, SC);
    const bf16x8 qA1 = cvt8s(qb + (size_t)(wq * 16 + c16) * DIM + 32 + quad * 8, SC);

    // qp[64][129] = (SC*Q)(64x64) . pos_table^T ; jt tiles split across wk
    {
        const int jt0 = wk ? 5 : 0, jt1 = wk ? 9 : 5;
        for (int jt = jt0; jt < jt1; ++jt) {
            int j0 = jt * 16;
            int jr = min(j0 + c16, 128);
            bf16x8 b0 = cvt8(ptg + (size_t)jr * DIM + quad * 8);
            bf16x8 b1 = cvt8(ptg + (size_t)jr * DIM + 32 + quad * 8);
            f32x4 acc = {0.f, 0.f, 0.f, 0.f};
            acc = __builtin_amdgcn_mfma_f32_16x16x32_bf16(qA0, b0, acc, 0, 0, 0);
            acc = __builtin_amdgcn_mfma_f32_16x16x32_bf16(qA1, b1, acc, 0, 0, 0);
            int jcol = j0 + c16;
            if (jcol <= 128) {
#pragma unroll
                for (int r = 0; r < 4; ++r)
                    qp[wq * 16 + quad * 4 + r][jcol] = acc[r];
            }
        }
    }
    __syncthreads();   // qp complete (both halves)

    // per-row saturation constants (one broadcast LDS read each)
    float cL[4], cR[4];
#pragma unroll
    for (int r = 0; r < 4; ++r) {
        cL[r] = qp[wq * 16 + quad * 4 + r][0];
        cR[r] = qp[wq * 16 + quad * 4 + r][128];
    }

    const u16* kb_base  = kbf + (size_t)b * SEQ * DIM;
    const u16* vtb_base = vt  + (size_t)b * DIM * SEQ;
    const int  row_min  = q0 + wq * 16;
    const int  ktbase   = wk * 8;

    // int-mask source for this lane: row q0+wq*16+(lane>>2), 16-int chunk (lane&3)
    const int* mrow = maskg + ((size_t)b * SEQ + q0 + wq * 16 + (lane >> 2)) * SEQ +
                      (lane & 3) * 16;

    // 2-deep mask prefetch: mreg[0] = tile ktbase, mreg[1] = tile ktbase+1
    u32x4 mreg[2][4];
#pragma unroll
    for (int s = 0; s < 2; ++s) {
        const int* p = mrow + (size_t)(ktbase + s) * 64;
        mreg[s][0] = *reinterpret_cast<const u32x4*>(p);
        mreg[s][1] = *reinterpret_cast<const u32x4*>(p + 4);
        mreg[s][2] = *reinterpret_cast<const u32x4*>(p + 8);
        mreg[s][3] = *reinterpret_cast<const u32x4*>(p + 12);
    }

    // ---- software-pipeline prologue ---------------------------------------
    bf16x8 kc0[4], kc1[4];
    bf16x8 vf0[4], vf1[4];
    f32x4  S_cur[4];

    // K(0) fragments
#pragma unroll
    for (int sub = 0; sub < 4; ++sub) {
        const u16* kr = kb_base + (size_t)(ktbase * 64 + sub * 16 + c16) * DIM;
        kc0[sub] = ldg8(kr + quad * 8);
        kc1[sub] = ldg8(kr + 32 + quad * 8);
    }
    // S(0) (one-time wait on K(0))
    __builtin_amdgcn_s_setprio(1);
#pragma unroll
    for (int sub = 0; sub < 4; ++sub) {
        f32x4 acc = {0.f, 0.f, 0.f, 0.f};
        acc = __builtin_amdgcn_mfma_f32_16x16x32_bf16(qA0, kc0[sub], acc, 0, 0, 0);
        acc = __builtin_amdgcn_mfma_f32_16x16x32_bf16(qA1, kc1[sub], acc, 0, 0, 0);
        S_cur[sub] = acc;
    }
    __builtin_amdgcn_s_setprio(0);
    // V(0) issued now, consumed at PV(0) (a full exp+S phase of cover)
#pragma unroll
    for (int d = 0; d < 4; ++d) {
        const u16* vr = vtb_base + (size_t)(d * 16 + c16) * SEQ + ktbase * 64;
        vf0[d] = ldg8(vr + quad * 8);
        vf1[d] = ldg8(vr + 32 + quad * 8);
    }
    // K(1) issued now, consumed at S(1) next iteration
#pragma unroll
    for (int sub = 0; sub < 4; ++sub) {
        const u16* kr = kb_base + (size_t)((ktbase + 1) * 64 + sub * 16 + c16) * DIM;
        kc0[sub] = ldg8(kr + quad * 8);
        kc1[sub] = ldg8(kr + 32 + quad * 8);
    }

    float l_part[4];
    f32x4 O[4];
#pragma unroll
    for (int r = 0; r < 4; ++r) l_part[r] = 0.f;
#pragma unroll
    for (int d = 0; d < 4; ++d) O[d] = f32x4{0.f, 0.f, 0.f, 0.f};

#pragma unroll
    for (int j = 0; j < 8; ++j) {
        const int kt = ktbase + j;
        const int k0 = kt * 64;
        const int ms = j & 1;          // static after full unroll

        // --- mask stage for tile j (per-wave LDS, in-order, no barrier) ----
        {
            u32x4 pk;
            pk[0] = pack4(mreg[ms][0]); pk[1] = pack4(mreg[ms][1]);
            pk[2] = pack4(mreg[ms][2]); pk[3] = pack4(mreg[ms][3]);
            *reinterpret_cast<u32x4*>(&mlds[wave][lane >> 2][(lane & 3) * 16]) = pk;
        }
        {   // refill this set with tile kt+2 (wrapped in-bounds; tail unused)
            const int* p = mrow + (size_t)((kt + 2) & 15) * 64;
            mreg[ms][0] = *reinterpret_cast<const u32x4*>(p);
            mreg[ms][1] = *reinterpret_cast<const u32x4*>(p + 4);
            mreg[ms][2] = *reinterpret_cast<const u32x4*>(p + 8);
            mreg[ms][3] = *reinterpret_cast<const u32x4*>(p + 12);
        }

        // --- exp(j) from CARRIED S_cur: no memory dependency ---------------
        const bool farL = (k0 + 127 <= row_min);
        const bool farR = (k0 >= row_min + 79);

        if (farL | farR) {
#pragma unroll
            for (int r = 0; r < 4; ++r) {
                const int row_l = quad * 4 + r;
                const float c = farL ? cL[r] : cR[r];
                float rs = 0.f;
#pragma unroll
                for (int sub = 0; sub < 4; ++sub) {
                    u8 mv = mlds[wave][row_l][sub * 16 + c16];
                    float e = mv ? 0.f : fexp2(S_cur[sub][r] + c);
                    rs += e;
                    plds[wave][row_l][sub * 16 + c16] = f2bf(e);
                }
                l_part[r] += rs;
            }
        } else {
#pragma unroll
            for (int r = 0; r < 4; ++r) {
                const int row_l = quad * 4 + r;
                const int row_g = row_min + row_l;
                float rs = 0.f;
#pragma unroll
                for (int sub = 0; sub < 4; ++sub) {
                    int col_g = k0 + sub * 16 + c16;
                    int rel = col_g - row_g;
                    rel = rel < -64 ? -64 : (rel > 64 ? 64 : rel);
                    float x = S_cur[sub][r] + qp[wq * 16 + row_l][rel + 64];
                    u8 mv = mlds[wave][row_l][sub * 16 + c16];
                    float e = mv ? 0.f : fexp2(x);
                    rs += e;
                    plds[wave][row_l][sub * 16 + c16] = f2bf(e);
                }
                l_part[r] += rs;
            }
        }

        // --- S(j+1) from K loaded last iter (covers plds write->read) ------
        if (j < 7) {
            __builtin_amdgcn_s_setprio(1);
#pragma unroll
            for (int sub = 0; sub < 4; ++sub) {
                f32x4 acc = {0.f, 0.f, 0.f, 0.f};
                acc = __builtin_amdgcn_mfma_f32_16x16x32_bf16(qA0, kc0[sub], acc, 0, 0, 0);
                acc = __builtin_amdgcn_mfma_f32_16x16x32_bf16(qA1, kc1[sub], acc, 0, 0, 0);
                S_cur[sub] = acc;
            }
            __builtin_amdgcn_s_setprio(0);
        }

        // --- PV(j) from V issued a full iteration ago ----------------------
        bf16x8 pA0 = *reinterpret_cast<bf16x8*>(&plds[wave][c16][quad * 8]);
        bf16x8 pA1 = *reinterpret_cast<bf16x8*>(&plds[wave][c16][32 + quad * 8]);
        __builtin_amdgcn_s_setprio(1);
#pragma unroll
        for (int d = 0; d < 4; ++d) {
            O[d] = __builtin_amdgcn_mfma_f32_16x16x32_bf16(pA0, vf0[d], O[d], 0, 0, 0);
            O[d] = __builtin_amdgcn_mfma_f32_16x16x32_bf16(pA1, vf1[d], O[d], 0, 0, 0);
        }
        __builtin_amdgcn_s_setprio(0);

        // --- issue V(j+1) and K(j+2) for future iterations -----------------
        if (j < 7) {
            const int k0n = k0 + 64;
#pragma unroll
            for (int d = 0; d < 4; ++d) {
                const u16* vr = vtb_base + (size_t)(d * 16 + c16) * SEQ + k0n;
                vf0[d] = ldg8(vr + quad * 8);
                vf1[d] = ldg8(vr + 32 + quad * 8);
            }
            const int kn = (ktbase + ((j + 2) & 7)) * 64;   // wrapped in-bounds
#pragma unroll
            for (int sub = 0; sub < 4; ++sub) {
                const u16* kr = kb_base + (size_t)(kn + sub * 16 + c16) * DIM;
                kc0[sub] = ldg8(kr + quad * 8);
                kc1[sub] = ldg8(kr + 32 + quad * 8);
            }
        }
    }

    // --- one l reduce at the end -------------------------------------------
    float l_run[4];
#pragma unroll
    for (int r = 0; r < 4; ++r) {
        float rs = l_part[r];
        rs += __shfl_xor(rs, 1);
        rs += __shfl_xor(rs, 2);
        rs += __shfl_xor(rs, 4);
        rs += __shfl_xor(rs, 8);
        l_run[r] = rs;
    }

    // --- merge the two K-halves: plain adds (same zero shift both) ---------
    __syncthreads();   // everyone done reading qp
    float* cmb = &qp[0][0];
    const int cbase = (wq * 64 + lane) * 24;
    if (wk == 1) {
#pragma unroll
        for (int r = 0; r < 4; ++r) cmb[cbase + r] = l_run[r];
#pragma unroll
        for (int d = 0; d < 4; ++d)
#pragma unroll
            for (int r = 0; r < 4; ++r)
                cmb[cbase + 4 + d * 4 + r] = O[d][r];
    }
    __syncthreads();
    if (wk == 0) {
        float* ob = outg + ((size_t)b * SEQ + q0) * DIM;
#pragma unroll
        for (int r = 0; r < 4; ++r) {
            float inv = 1.f / (l_run[r] + cmb[cbase + r]);
            int row_l = wq * 16 + quad * 4 + r;
#pragma unroll
            for (int d = 0; d < 4; ++d) {
                float o = O[d][r] + cmb[cbase + 4 + d * 4 + r];
                ob[(size_t)row_l * DIM + d * 16 + c16] = o * inv;
            }
        }
    }
}

// ---------------------------------------------------------------------------
// Fallback kernels (workspace too small for fast path).
// ---------------------------------------------------------------------------
__global__ __launch_bounds__(256) void vt_kernel(const float* __restrict__ v,
                                                 u16* __restrict__ vt) {
    __shared__ u16 tile[64][72];
    const int b  = blockIdx.y;
    const int k0 = blockIdx.x * 64;
    const int t  = threadIdx.x;
    const float* vb  = v  + (size_t)b * SEQ * DIM;
    u16*         vtb = vt + (size_t)b * DIM * SEQ;

    {
        int kk = t >> 2;
        int d0 = (t & 3) * 16;
        const float* src = vb + (size_t)(k0 + kk) * DIM + d0;
        u16 tmp[16];
#pragma unroll
        for (int i = 0; i < 4; ++i) {
            f32x4 a = *reinterpret_cast<const f32x4*>(src + i * 4);
            tmp[i * 4 + 0] = f2bf(a[0]); tmp[i * 4 + 1] = f2bf(a[1]);
            tmp[i * 4 + 2] = f2bf(a[2]); tmp[i * 4 + 3] = f2bf(a[3]);
        }
        *reinterpret_cast<u32x4*>(&tile[kk][d0])     = *reinterpret_cast<u32x4*>(tmp);
        *reinterpret_cast<u32x4*>(&tile[kk][d0 + 8]) = *reinterpret_cast<u32x4*>(tmp + 8);
    }
    __syncthreads();
#pragma unroll
    for (int i = 0; i < 2; ++i) {
        int d  = t / 8 + i * 32;
        int ks = (t % 8) * 8;
        u16 tmp[8];
#pragma unroll
        for (int j = 0; j < 8; ++j) tmp[j] = tile[ks + j][d];
        *reinterpret_cast<u32x4*>(vtb + (size_t)d * SEQ + k0 + ks) =
            *reinterpret_cast<u32x4*>(tmp);
    }
}

template <bool USE_VT>
__global__ __launch_bounds__(256, 2) void attn_kernel(
    const float* __restrict__ qg, const float* __restrict__ kg,
    const void* __restrict__ vgv, const int* __restrict__ maskg,
    const float* __restrict__ ptg, float* __restrict__ outg) {
    __shared__ float qp[64][132];
    __shared__ int   mlds[4][16][68];
    __shared__ u16   plds[4][16][72];

    const int b    = blockIdx.y;
    const int q0   = blockIdx.x * 64;
    const int tid  = threadIdx.x;
    const int wave = tid >> 6;
    const int lane = tid & 63;
    const int quad = lane >> 4;
    const int c16  = lane & 15;

    const float* qb = qg + ((size_t)b * SEQ + q0) * DIM;
    const float* kb = kg + (size_t)b * SEQ * DIM;
    const int*   mb = maskg + ((size_t)b * SEQ + q0) * SEQ;

    const bf16x8 qA0 = cvt8(qb + (size_t)(wave * 16 + c16) * DIM + quad * 8);
    const bf16x8 qA1 = cvt8(qb + (size_t)(wave * 16 + c16) * DIM + 32 + quad * 8);

    for (int jt = 0; jt < 9; ++jt) {
        int j0 = jt * 16;
        int jr = min(j0 + c16, 128);
        bf16x8 b0 = cvt8(ptg + (size_t)jr * DIM + quad * 8);
        bf16x8 b1 = cvt8(ptg + (size_t)jr * DIM + 32 + quad * 8);
        f32x4 acc = {0.f, 0.f, 0.f, 0.f};
        acc = __builtin_amdgcn_mfma_f32_16x16x32_bf16(qA0, b0, acc, 0, 0, 0);
        acc = __builtin_amdgcn_mfma_f32_16x16x32_bf16(qA1, b1, acc, 0, 0, 0);
        int jcol = j0 + c16;
        if (jcol <= 128) {
#pragma unroll
            for (int r = 0; r < 4; ++r)
                qp[wave * 16 + quad * 4 + r][jcol] = acc[r];
        }
    }

    float m_run[4], l_run[4];
    f32x4 O[4];
#pragma unroll
    for (int r = 0; r < 4; ++r) { m_run[r] = -1e30f; l_run[r] = 0.f; }
#pragma unroll
    for (int d = 0; d < 4; ++d) O[d] = f32x4{0.f, 0.f, 0.f, 0.f};

#pragma unroll 1
    for (int kt = 0; kt < NKT; ++kt) {
        const int k0 = kt * 64;
        {
            int row_l = lane >> 2;
            const int* mrow = mb + (size_t)(wave * 16 + row_l) * SEQ + k0;
#pragma unroll
            for (int i = 0; i < 4; ++i) {
                int seg = (lane & 3) + i * 4;
                *reinterpret_cast<u32x4*>(&mlds[wave][row_l][seg * 4]) =
                    *reinterpret_cast<const u32x4*>(mrow + seg * 4);
            }
        }

        f32x4 S[4];
#pragma unroll
        for (int sub = 0; sub < 4; ++sub) {
            const float* kr = kb + (size_t)(k0 + sub * 16 + c16) * DIM;
            bf16x8 kb0 = cvt8(kr + quad * 8);
            bf16x8 kb1 = cvt8(kr + 32 + quad * 8);
            f32x4 acc = {0.f, 0.f, 0.f, 0.f};
            acc = __builtin_amdgcn_mfma_f32_16x16x32_bf16(qA0, kb0, acc, 0, 0, 0);
            acc = __builtin_amdgcn_mfma_f32_16x16x32_bf16(qA1, kb1, acc, 0, 0, 0);
            S[sub] = acc;
        }

        float sv[4][4];
#pragma unroll
        for (int sub = 0; sub < 4; ++sub) {
#pragma unroll
            for (int r = 0; r < 4; ++r) {
                int row_l = quad * 4 + r;
                int row_g = q0 + wave * 16 + row_l;
                int col_g = k0 + sub * 16 + c16;
                int rel = col_g - row_g;
                rel = rel < -64 ? -64 : (rel > 64 ? 64 : rel);
                float x = (S[sub][r] + qp[wave * 16 + row_l][rel + 64]) * 0.125f;
                int mv = mlds[wave][row_l][sub * 16 + c16];
                sv[sub][r] = mv ? -1e30f : x;
            }
        }

        float m_new[4], alpha[4];
#pragma unroll
        for (int r = 0; r < 4; ++r) {
            float rmax = fmaxf(fmaxf(sv[0][r], sv[1][r]), fmaxf(sv[2][r], sv[3][r]));
            rmax = fmaxf(rmax, __shfl_xor(rmax, 1));
            rmax = fmaxf(rmax, __shfl_xor(rmax, 2));
            rmax = fmaxf(rmax, __shfl_xor(rmax, 4));
            rmax = fmaxf(rmax, __shfl_xor(rmax, 8));
            m_new[r] = fmaxf(m_run[r], rmax);
            alpha[r] = __expf(m_run[r] - m_new[r]);
            m_run[r] = m_new[r];
        }
#pragma unroll
        for (int r = 0; r < 4; ++r) {
            float rs = 0.f;
#pragma unroll
            for (int sub = 0; sub < 4; ++sub) {
                float e = __expf(sv[sub][r] - m_new[r]);
                rs += e;
                plds[wave][quad * 4 + r][sub * 16 + c16] = f2bf(e);
            }
            rs += __shfl_xor(rs, 1);
            rs += __shfl_xor(rs, 2);
            rs += __shfl_xor(rs, 4);
            rs += __shfl_xor(rs, 8);
            l_run[r] = l_run[r] * alpha[r] + rs;
#pragma unroll
            for (int d = 0; d < 4; ++d) O[d][r] *= alpha[r];
        }

        bf16x8 pA0 = *reinterpret_cast<bf16x8*>(&plds[wave][c16][quad * 8]);
        bf16x8 pA1 = *reinterpret_cast<bf16x8*>(&plds[wave][c16][32 + quad * 8]);
#pragma unroll
        for (int d = 0; d < 4; ++d) {
            bf16x8 vb0, vb1;
            if (USE_VT) {
                const u16* vtb = (const u16*)vgv + (size_t)b * DIM * SEQ +
                                 (size_t)(d * 16 + c16) * SEQ + k0;
                vb0 = ldg8(vtb + quad * 8);
                vb1 = ldg8(vtb + 32 + quad * 8);
            } else {
                u16 t0[8], t1[8];
                const float* vbase = (const float*)vgv +
                                     ((size_t)b * SEQ + k0) * DIM + d * 16 + c16;
#pragma unroll
                for (int jj = 0; jj < 8; ++jj) {
                    t0[jj] = f2bf(vbase[(size_t)(quad * 8 + jj) * DIM]);
                    t1[jj] = f2bf(vbase[(size_t)(32 + quad * 8 + jj) * DIM]);
                }
                vb0 = __builtin_bit_cast(bf16x8, *reinterpret_cast<u32x4*>(t0));
                vb1 = __builtin_bit_cast(bf16x8, *reinterpret_cast<u32x4*>(t1));
            }
            O[d] = __builtin_amdgcn_mfma_f32_16x16x32_bf16(pA0, vb0, O[d], 0, 0, 0);
            O[d] = __builtin_amdgcn_mfma_f32_16x16x32_bf16(pA1, vb1, O[d], 0, 0, 0);
        }
    }

    float* ob = outg + ((size_t)b * SEQ + q0) * DIM;
#pragma unroll
    for (int r = 0; r < 4; ++r) {
        float inv = 1.f / l_run[r];
        int row_l = wave * 16 + quad * 4 + r;
#pragma unroll
        for (int d = 0; d < 4; ++d)
            ob[(size_t)row_l * DIM + d * 16 + c16] = O[d][r] * inv;
    }
}

// ---------------------------------------------------------------------------
extern "C" void kernel_launch(void* const* d_in, const int* in_sizes, int n_in,
                              void* d_out, int out_size, void* d_ws, size_t ws_size,
                              hipStream_t stream) {
    const float* q    = (const float*)d_in[0];
    const float* k    = (const float*)d_in[1];
    const float* v    = (const float*)d_in[2];
    const int*   mask = (const int*)d_in[3];
    const float* pt   = (const float*)d_in[4];
    float* out        = (float*)d_out;

    const size_t vt_bytes = (size_t)BATCH * SEQ * DIM * sizeof(u16);   // 4 MB
    const size_t kb_bytes = (size_t)BATCH * SEQ * DIM * sizeof(u16);   // 4 MB
    dim3 grid(SEQ / 64, BATCH);

    if (ws_size >= vt_bytes + kb_bytes) {
        u16* vt = (u16*)d_ws;
        u16* kb = (u16*)((char*)d_ws + vt_bytes);
        prep_kv<<<dim3(512), 256, 0, stream>>>(k, v, kb, vt);
        attn_fast13<<<grid, 512, 0, stream>>>(q, kb, vt, mask, pt, out);
    } else if (ws_size >= vt_bytes) {
        u16* vt = (u16*)d_ws;
        vt_kernel<<<grid, 256, 0, stream>>>(v, vt);
        attn_kernel<true><<<grid, 256, 0, stream>>>(q, k, (const void*)vt, mask, pt, out);
    } else {
        attn_kernel<false><<<grid, 256, 0, stream>>>(q, k, (const void*)v, mask, pt, out);
    }
}